// Round 5
// baseline (127.581 us; speedup 1.0000x reference)
//
#include <hip/hip_runtime.h>

// Problem constants (fixed by the reference setup)
#define P_ 4
#define B_ 8
#define NPIX 65536              // H*W
#define G_ 4
#define C_ 12
#define CHUNKS 64               // chunks per batch
#define NBLK (B_ * CHUNKS)      // 512 blocks (2 per CU)
#define TILE (NPIX / CHUNKS)    // 1024 pixels per block
#define ROUNDS (TILE / 64)      // 16 rounds per wave
#define NSLOT (C_ * B_ * 21)    // 2016 sum-slots
#define RSTRIDE 65              // padded LDS row stride (odd -> conflict-free)
#define SCALE 16777216.0        // 2^24 fixed-point scale
// ws layout: int64 slots[NSLOT] (fixed-point sums), then uint counter at byte NSLOT*8.
// slot = (c*B_ + b)*21 + i;  i: 0..15 = W[a][g], 16..19 = Z[a], 20 = count

__global__ __launch_bounds__(256, 2) void kld_fused(
    const float* __restrict__ act,     // [P, B, N, G]
    const int*   __restrict__ labels,  // [B, N]
    const float* __restrict__ gci,     // [P*G, C]
    const float* __restrict__ proto,   // [120, C]
    unsigned long long* __restrict__ slots,
    float* __restrict__ out)
{
    __shared__ float red[4 * 63 * RSTRIDE];   // 65,520 B
    __shared__ float s_sum[NSLOT];
    __shared__ float s_ok[C_];
    __shared__ float s_tot[128];
    __shared__ float s_den[128];
    __shared__ int   s_last;

    const int b     = blockIdx.x / CHUNKS;
    const int chunk = blockIdx.x % CHUNKS;
    const int t     = threadIdx.x;
    const int w     = t >> 6;                 // wave id 0..3
    const int lane  = t & 63;
    const int cls[3] = { w, w + 4, w + 8 };   // this wave's classes

    // proj_idx for my 3 classes (argmax over 16 rows, first max, /G), scalarized
    int pj[3];
    #pragma unroll
    for (int k = 0; k < 3; ++k) {
        int best = 0; float bv = gci[cls[k]];
        #pragma unroll
        for (int r = 1; r < P_ * G_; ++r) {
            const float v = gci[r * C_ + cls[k]];
            if (v > bv) { bv = v; best = r; }
        }
        pj[k] = __builtin_amdgcn_readfirstlane(best >> 2);
    }
    const bool same = (pj[1] == pj[0]) && (pj[2] == pj[0]);   // wave-uniform

    const int* __restrict__ lab = labels + (size_t)b * NPIX + chunk * TILE;
    int lv[ROUNDS];
    #pragma unroll
    for (int r = 0; r < ROUNDS; ++r) lv[r] = lab[r * 64 + lane];

    float acc[63];
    #pragma unroll
    for (int i = 0; i < 63; ++i) acc[i] = 0.0f;

    if (same) {
        // FAST PATH: dense coalesced stream of the one plane covering all 3 classes
        const float4* __restrict__ pp = reinterpret_cast<const float4*>(
            act + ((size_t)(pj[0] * B_ + b) * NPIX + (size_t)chunk * TILE) * G_);
        #pragma unroll
        for (int r = 0; r < ROUNDS; ++r) {
            const float4 v = pp[r * 64 + lane];
            const int l   = lv[r];
            const int cef = ((unsigned)(l - 1) < (unsigned)C_) ? (l - 1) : 255;
            const float vv[4] = { v.x, v.y, v.z, v.w };
            float ee[4], wag[16];
            #pragma unroll
            for (int a = 0; a < 4; ++a) ee[a] = __expf(vv[a]);
            #pragma unroll
            for (int a = 0; a < 4; ++a)
                #pragma unroll
                for (int g = 0; g < 4; ++g) wag[a * 4 + g] = ee[a] * vv[g];
            #pragma unroll
            for (int k = 0; k < 3; ++k) {
                const float m = (cef == cls[k]) ? 1.0f : 0.0f;   // predicated
                acc[k * 21 + 20] += m;
                #pragma unroll
                for (int a = 0; a < 4; ++a)
                    acc[k * 21 + 16 + a] = fmaf(m, ee[a], acc[k * 21 + 16 + a]);
                #pragma unroll
                for (int i = 0; i < 16; ++i)
                    acc[k * 21 + i] = fmaf(m, wag[i], acc[k * 21 + i]);
            }
        }
    } else {
        // FALLBACK (general gci): masked gather per class
        for (int r = 0; r < ROUNDS; ++r) {
            const int n   = chunk * TILE + r * 64 + lane;
            const int l   = lv[r];
            const int cef = ((unsigned)(l - 1) < (unsigned)C_) ? (l - 1) : 255;
            #pragma unroll
            for (int k = 0; k < 3; ++k) {
                if (cef == cls[k]) {
                    const float4 v = *reinterpret_cast<const float4*>(
                        act + (((size_t)(pj[k] * B_ + b) * NPIX) + (size_t)n) * G_);
                    const float vv[4] = { v.x, v.y, v.z, v.w };
                    #pragma unroll
                    for (int a = 0; a < 4; ++a) {
                        const float e = __expf(vv[a]);
                        acc[k * 21 + 16 + a] += e;
                        #pragma unroll
                        for (int g = 0; g < 4; ++g)
                            acc[k * 21 + a * 4 + g] = fmaf(e, vv[g], acc[k * 21 + a * 4 + g]);
                    }
                    acc[k * 21 + 20] += 1.0f;
                }
            }
        }
    }

    // block reduce: LDS transpose (conflict-free via odd row stride)
    float* base = red + w * 63 * RSTRIDE;
    #pragma unroll
    for (int i = 0; i < 63; ++i) base[i * RSTRIDE + lane] = acc[i];
    __syncthreads();
    if (lane < 63) {
        float s = 0.0f;
        #pragma unroll
        for (int j = 0; j < 64; ++j) s += base[lane * RSTRIDE + j];
        const int k = lane / 21, i = lane % 21;
        const int c = w + k * 4;
        // fixed-point flush: native int64 atomic (fire-and-forget, no CAS loop)
        const long long q = (long long)((double)s * SCALE);
        atomicAdd(slots + ((size_t)c * B_ + b) * 21 + i, (unsigned long long)q);
    }

    // ---- last-block-done finalize ----
    __threadfence();          // drain my atomics device-wide
    __syncthreads();
    unsigned int* counter = (unsigned int*)(slots + NSLOT);
    if (t == 0) {
        const unsigned int ret = atomicAdd(counter, 1u);
        s_last = (ret == (unsigned int)(NBLK - 1)) ? 1 : 0;
    }
    __syncthreads();
    if (!s_last) return;

    // I'm the last block: every other block's atomics are complete.
    // Read slots coherently via atomicAdd(p, 0) (cross-XCD safe by construction).
    const float inv = (float)(1.0 / SCALE);
    for (int s = t; s < NSLOT; s += 256) {
        const unsigned long long q = atomicAdd(slots + s, 0ULL);
        s_sum[s] = (float)((double)(long long)q * (double)inv);
    }
    if (t < C_) {   // proto_ok[c] = column sum > 0
        float s = 0.0f;
        #pragma unroll
        for (int r = 0; r < 120; ++r) s += proto[r * C_ + t];
        s_ok[t] = s;
    }
    __syncthreads();

    float tot = 0.0f, den = 0.0f;
    if (t < C_ * B_) {
        const int c = t / B_;
        const float* slot = s_sum + t * 21;
        const float cnt = slot[20];
        if (s_ok[c] > 0.0f && cnt >= 2.0f) {
            float S[4][4];
            #pragma unroll
            for (int a = 0; a < 4; ++a) {
                const float zinv = 1.0f / slot[16 + a];
                #pragma unroll
                for (int g = 0; g < 4; ++g)
                    S[a][g] = slot[a * 4 + g] * zinv;
            }
            #pragma unroll
            for (int j = 0; j < 4; ++j)
                #pragma unroll
                for (int k = 0; k < 4; ++k)
                    if (k > j) {
                        const float kld = 0.5f * (S[j][j] + S[k][k] - S[j][k] - S[k][j]);
                        tot += __expf(-kld);
                    }
            den = 6.0f;   // G*(G-1)/2 pairs
        }
    }

    if (t < 128) { s_tot[t] = tot; s_den[t] = den; }
    __syncthreads();
    #pragma unroll
    for (int s = 64; s >= 1; s >>= 1) {
        if (t < s) { s_tot[t] += s_tot[t + s]; s_den[t] += s_den[t + s]; }
        __syncthreads();
    }
    if (t == 0)
        out[0] = (s_den[0] > 0.0f) ? (s_tot[0] / s_den[0]) : 0.0f;
}

extern "C" void kernel_launch(void* const* d_in, const int* in_sizes, int n_in,
                              void* d_out, int out_size, void* d_ws, size_t ws_size,
                              hipStream_t stream) {
    const float* act    = (const float*)d_in[0];  // [P,B,N,G] fp32
    const int*   labels = (const int*)d_in[1];    // [B,H,W] int32
    const float* proto  = (const float*)d_in[2];  // [120, C] fp32
    const float* gci    = (const float*)d_in[3];  // [P*G, C] fp32
    float* out = (float*)d_out;
    unsigned long long* slots = (unsigned long long*)d_ws;

    // zero the 2016 int64 slots + the completion counter (16 KB + pad)
    hipMemsetAsync(d_ws, 0, NSLOT * 8 + 64, stream);
    kld_fused<<<NBLK, 256, 0, stream>>>(act, labels, gci, proto, slots, out);
}

// Round 6
// 100.067 us; speedup vs baseline: 1.2750x; 1.2750x over previous
//
#include <hip/hip_runtime.h>

// Problem constants (fixed by the reference setup)
#define P_ 4
#define B_ 8
#define NPIX 65536              // H*W
#define G_ 4
#define C_ 12
#define CHUNKS 32               // chunks per batch
#define NBLK (B_ * CHUNKS)      // 256 stage-1 blocks (1 per CU)
#define TILE (NPIX / CHUNKS)    // 2048 pixels per block
#define HALF 16                 // rounds per half (2 halves = 32 rounds)
#define NSLOT (C_ * B_ * 21)    // 2016 sum-slots
#define RSTRIDE 65              // padded LDS row stride (odd -> conflict-free)
// ws layout: partials[chunk][slot], slot = (c*B_ + b)*21 + i
// i: 0..15 = W[a][g], 16..19 = Z[a], 20 = count

__global__ __launch_bounds__(256, 2) void kld_stage1(
    const float* __restrict__ act,     // [P, B, N, G]
    const int*   __restrict__ labels,  // [B, N]
    const float* __restrict__ gci,     // [P*G, C]
    float*       __restrict__ partials)
{
    __shared__ float red[4 * 63 * RSTRIDE];   // 65,520 B
    const int b     = blockIdx.x / CHUNKS;
    const int chunk = blockIdx.x % CHUNKS;
    const int w     = threadIdx.x >> 6;       // wave id 0..3
    const int lane  = threadIdx.x & 63;
    const int cls[3] = { w, w + 4, w + 8 };   // this wave's classes

    // proj_idx for my 3 classes (argmax over 16 rows, first max, /G), scalarized
    int pj[3];
    #pragma unroll
    for (int k = 0; k < 3; ++k) {
        int best = 0; float bv = gci[cls[k]];
        #pragma unroll
        for (int r = 1; r < P_ * G_; ++r) {
            const float v = gci[r * C_ + cls[k]];
            if (v > bv) { bv = v; best = r; }
        }
        pj[k] = __builtin_amdgcn_readfirstlane(best >> 2);
    }
    const bool same = (pj[1] == pj[0]) && (pj[2] == pj[0]);   // wave-uniform

    const int* __restrict__ lab = labels + (size_t)b * NPIX + chunk * TILE;

    float acc[63];
    #pragma unroll
    for (int i = 0; i < 63; ++i) acc[i] = 0.0f;

    if (same) {
        // FAST PATH: dense coalesced stream of the one plane covering all 3 classes
        const float4* __restrict__ pp = reinterpret_cast<const float4*>(
            act + ((size_t)(pj[0] * B_ + b) * NPIX + (size_t)chunk * TILE) * G_);
        for (int h = 0; h < 2; ++h) {
            #pragma unroll
            for (int r = 0; r < HALF; ++r) {
                const int rr = h * HALF + r;
                const float4 v = pp[rr * 64 + lane];
                const int l   = lab[rr * 64 + lane];
                const int cef = ((unsigned)(l - 1) < (unsigned)C_) ? (l - 1) : 255;
                const float vv[4] = { v.x, v.y, v.z, v.w };
                float ee[4], wag[16];
                #pragma unroll
                for (int a = 0; a < 4; ++a) ee[a] = __expf(vv[a]);
                #pragma unroll
                for (int a = 0; a < 4; ++a)
                    #pragma unroll
                    for (int g = 0; g < 4; ++g) wag[a * 4 + g] = ee[a] * vv[g];
                #pragma unroll
                for (int k = 0; k < 3; ++k) {
                    const float m = (cef == cls[k]) ? 1.0f : 0.0f;   // predicated
                    acc[k * 21 + 20] += m;
                    #pragma unroll
                    for (int a = 0; a < 4; ++a)
                        acc[k * 21 + 16 + a] = fmaf(m, ee[a], acc[k * 21 + 16 + a]);
                    #pragma unroll
                    for (int i = 0; i < 16; ++i)
                        acc[k * 21 + i] = fmaf(m, wag[i], acc[k * 21 + i]);
                }
            }
        }
    } else {
        // FALLBACK (general gci): masked gather per class
        for (int rr = 0; rr < 2 * HALF; ++rr) {
            const int n   = chunk * TILE + rr * 64 + lane;
            const int l   = lab[rr * 64 + lane];
            const int cef = ((unsigned)(l - 1) < (unsigned)C_) ? (l - 1) : 255;
            #pragma unroll
            for (int k = 0; k < 3; ++k) {
                if (cef == cls[k]) {
                    const float4 v = *reinterpret_cast<const float4*>(
                        act + (((size_t)(pj[k] * B_ + b) * NPIX) + (size_t)n) * G_);
                    const float vv[4] = { v.x, v.y, v.z, v.w };
                    #pragma unroll
                    for (int a = 0; a < 4; ++a) {
                        const float e = __expf(vv[a]);
                        acc[k * 21 + 16 + a] += e;
                        #pragma unroll
                        for (int g = 0; g < 4; ++g)
                            acc[k * 21 + a * 4 + g] = fmaf(e, vv[g], acc[k * 21 + a * 4 + g]);
                    }
                    acc[k * 21 + 20] += 1.0f;
                }
            }
        }
    }

    // block reduce: LDS transpose (conflict-free via odd row stride)
    float* base = red + w * 63 * RSTRIDE;
    #pragma unroll
    for (int i = 0; i < 63; ++i) base[i * RSTRIDE + lane] = acc[i];
    __syncthreads();
    if (lane < 63) {
        float s = 0.0f;
        #pragma unroll
        for (int j = 0; j < 64; ++j) s += base[lane * RSTRIDE + j];
        const int k = lane / 21, i = lane % 21;
        const int c = w + k * 4;
        partials[(size_t)chunk * NSLOT + ((size_t)c * B_ + b) * 21 + i] = s;
    }
}

__global__ __launch_bounds__(1024) void kld_finalize(
    const float* __restrict__ partials,  // [CHUNKS][NSLOT]
    const float* __restrict__ proto,     // [120, C]
    float*       __restrict__ out)
{
    __shared__ float s_sum[NSLOT];
    __shared__ float s_ok[C_];
    __shared__ float s_tot[128];
    __shared__ float s_den[128];
    const int t = threadIdx.x;

    if (t < C_) {   // proto_ok[c] = column sum > 0
        float s = 0.0f;
        #pragma unroll
        for (int r = 0; r < 120; ++r) s += proto[r * C_ + t];
        s_ok[t] = s;
    }

    // phase 1: sum each slot over CHUNKS (coalesced: consecutive t -> consecutive addr)
    for (int s = t; s < NSLOT; s += 1024) {
        float a = 0.0f;
        #pragma unroll
        for (int q = 0; q < CHUNKS; ++q) a += partials[(size_t)q * NSLOT + s];
        s_sum[s] = a;
    }
    __syncthreads();

    // phase 2: one thread per (c,b) pair
    float tot = 0.0f, den = 0.0f;
    if (t < C_ * B_) {
        const int c = t / B_;
        const float* slot = s_sum + t * 21;
        const float cnt = slot[20];
        if (s_ok[c] > 0.0f && cnt >= 2.0f) {
            float S[4][4];
            #pragma unroll
            for (int a = 0; a < 4; ++a) {
                const float zinv = 1.0f / slot[16 + a];
                #pragma unroll
                for (int g = 0; g < 4; ++g)
                    S[a][g] = slot[a * 4 + g] * zinv;
            }
            #pragma unroll
            for (int j = 0; j < 4; ++j)
                #pragma unroll
                for (int k = 0; k < 4; ++k)
                    if (k > j) {
                        const float kld = 0.5f * (S[j][j] + S[k][k] - S[j][k] - S[k][j]);
                        tot += __expf(-kld);
                    }
            den = 6.0f;   // G*(G-1)/2 pairs
        }
    }

    if (t < 128) { s_tot[t] = tot; s_den[t] = den; }
    __syncthreads();
    #pragma unroll
    for (int s = 64; s >= 1; s >>= 1) {
        if (t < s) { s_tot[t] += s_tot[t + s]; s_den[t] += s_den[t + s]; }
        __syncthreads();
    }
    if (t == 0)
        out[0] = (s_den[0] > 0.0f) ? (s_tot[0] / s_den[0]) : 0.0f;
}

extern "C" void kernel_launch(void* const* d_in, const int* in_sizes, int n_in,
                              void* d_out, int out_size, void* d_ws, size_t ws_size,
                              hipStream_t stream) {
    const float* act    = (const float*)d_in[0];  // [P,B,N,G] fp32
    const int*   labels = (const int*)d_in[1];    // [B,H,W] int32
    const float* proto  = (const float*)d_in[2];  // [120, C] fp32
    const float* gci    = (const float*)d_in[3];  // [P*G, C] fp32
    float* out = (float*)d_out;
    float* ws  = (float*)d_ws;   // 258 KiB used; every element written by stage1

    kld_stage1<<<NBLK, 256, 0, stream>>>(act, labels, gci, ws);
    kld_finalize<<<1, 1024, 0, stream>>>(ws, proto, out);
}

// Round 7
// 88.706 us; speedup vs baseline: 1.4383x; 1.1281x over previous
//
#include <hip/hip_runtime.h>

// Problem constants (fixed by the reference setup)
#define P_ 4
#define B_ 8
#define NPIX 65536              // H*W
#define G_ 4
#define C_ 12
#define CHUNKS 64               // chunks per batch
#define NBLK (B_ * CHUNKS)      // 512 stage-1 blocks (2 per CU -> 8 waves/CU streaming)
#define TILE (NPIX / CHUNKS)    // 1024 pixels per block
#define ROUNDS (TILE / 64)      // 16 rounds per wave
#define NSLOT (C_ * B_ * 21)    // 2016 sum-slots
#define RSTRIDE 65              // padded LDS row stride (odd -> conflict-free)
// ws layout: partials[chunk][slot], slot = (c*B_ + b)*21 + i
// i: 0..15 = W[a][g], 16..19 = Z[a], 20 = count

__global__ __launch_bounds__(256, 2) void kld_stage1(
    const float* __restrict__ act,     // [P, B, N, G]
    const int*   __restrict__ labels,  // [B, N]
    const float* __restrict__ gci,     // [P*G, C]
    float*       __restrict__ partials)
{
    __shared__ float red[4 * 63 * RSTRIDE];   // 65,520 B -> 2 blocks/CU (the sweet spot)
    const int b     = blockIdx.x / CHUNKS;
    const int chunk = blockIdx.x % CHUNKS;
    const int w     = threadIdx.x >> 6;       // wave id 0..3
    const int lane  = threadIdx.x & 63;
    const int cls[3] = { w, w + 4, w + 8 };   // this wave's classes

    // proj_idx for my 3 classes (argmax over 16 rows, first max, /G), scalarized
    int pj[3];
    #pragma unroll
    for (int k = 0; k < 3; ++k) {
        int best = 0; float bv = gci[cls[k]];
        #pragma unroll
        for (int r = 1; r < P_ * G_; ++r) {
            const float v = gci[r * C_ + cls[k]];
            if (v > bv) { bv = v; best = r; }
        }
        pj[k] = __builtin_amdgcn_readfirstlane(best >> 2);
    }
    const bool same = (pj[1] == pj[0]) && (pj[2] == pj[0]);   // wave-uniform

    const int* __restrict__ lab = labels + (size_t)b * NPIX + chunk * TILE;
    int lv[ROUNDS];
    #pragma unroll
    for (int r = 0; r < ROUNDS; ++r) lv[r] = lab[r * 64 + lane];

    float acc[63];
    #pragma unroll
    for (int i = 0; i < 63; ++i) acc[i] = 0.0f;

    if (same) {
        // FAST PATH: dense coalesced stream of the one plane covering all 3 classes
        const float4* __restrict__ pp = reinterpret_cast<const float4*>(
            act + ((size_t)(pj[0] * B_ + b) * NPIX + (size_t)chunk * TILE) * G_);
        #pragma unroll
        for (int r = 0; r < ROUNDS; ++r) {
            const float4 v = pp[r * 64 + lane];
            const int l   = lv[r];
            const int cef = ((unsigned)(l - 1) < (unsigned)C_) ? (l - 1) : 255;
            const float vv[4] = { v.x, v.y, v.z, v.w };
            float ee[4], wag[16];
            #pragma unroll
            for (int a = 0; a < 4; ++a) ee[a] = __expf(vv[a]);
            #pragma unroll
            for (int a = 0; a < 4; ++a)
                #pragma unroll
                for (int g = 0; g < 4; ++g) wag[a * 4 + g] = ee[a] * vv[g];
            #pragma unroll
            for (int k = 0; k < 3; ++k) {
                const float m = (cef == cls[k]) ? 1.0f : 0.0f;   // predicated, no branch
                acc[k * 21 + 20] += m;
                #pragma unroll
                for (int a = 0; a < 4; ++a)
                    acc[k * 21 + 16 + a] = fmaf(m, ee[a], acc[k * 21 + 16 + a]);
                #pragma unroll
                for (int i = 0; i < 16; ++i)
                    acc[k * 21 + i] = fmaf(m, wag[i], acc[k * 21 + i]);
            }
        }
    } else {
        // FALLBACK (general gci): masked gather per class
        for (int r = 0; r < ROUNDS; ++r) {
            const int n   = chunk * TILE + r * 64 + lane;
            const int l   = lv[r];
            const int cef = ((unsigned)(l - 1) < (unsigned)C_) ? (l - 1) : 255;
            #pragma unroll
            for (int k = 0; k < 3; ++k) {
                if (cef == cls[k]) {
                    const float4 v = *reinterpret_cast<const float4*>(
                        act + (((size_t)(pj[k] * B_ + b) * NPIX) + (size_t)n) * G_);
                    const float vv[4] = { v.x, v.y, v.z, v.w };
                    #pragma unroll
                    for (int a = 0; a < 4; ++a) {
                        const float e = __expf(vv[a]);
                        acc[k * 21 + 16 + a] += e;
                        #pragma unroll
                        for (int g = 0; g < 4; ++g)
                            acc[k * 21 + a * 4 + g] = fmaf(e, vv[g], acc[k * 21 + a * 4 + g]);
                    }
                    acc[k * 21 + 20] += 1.0f;
                }
            }
        }
    }

    // block reduce: LDS transpose (conflict-free via odd row stride)
    float* base = red + w * 63 * RSTRIDE;
    #pragma unroll
    for (int i = 0; i < 63; ++i) base[i * RSTRIDE + lane] = acc[i];
    __syncthreads();
    if (lane < 63) {
        float s = 0.0f;
        #pragma unroll
        for (int j = 0; j < 64; ++j) s += base[lane * RSTRIDE + j];
        const int k = lane / 21, i = lane % 21;
        const int c = w + k * 4;
        partials[(size_t)chunk * NSLOT + ((size_t)c * B_ + b) * 21 + i] = s;
    }
}

__global__ __launch_bounds__(1024) void kld_finalize(
    const float* __restrict__ partials,  // [CHUNKS][NSLOT]
    const float* __restrict__ proto,     // [120, C]
    float*       __restrict__ out)
{
    __shared__ float s_sum[NSLOT];
    __shared__ float s_ok[C_];
    __shared__ float s_tot[128];
    __shared__ float s_den[128];
    const int t = threadIdx.x;

    if (t < C_) {   // proto_ok[c] = column sum > 0
        float s = 0.0f;
        #pragma unroll
        for (int r = 0; r < 120; ++r) s += proto[r * C_ + t];
        s_ok[t] = s;
    }

    // phase 1: sum slots over CHUNKS; thread t owns slots 4t..4t+3 (float4,
    // 16B-aligned: each q-row is 2016 contiguous floats). 504 threads active.
    if (t < NSLOT / 4) {
        float4 a = {0.f, 0.f, 0.f, 0.f};
        #pragma unroll
        for (int q = 0; q < CHUNKS; ++q) {
            const float4 v = *reinterpret_cast<const float4*>(
                partials + (size_t)q * NSLOT + 4 * t);
            a.x += v.x; a.y += v.y; a.z += v.z; a.w += v.w;
        }
        s_sum[4 * t + 0] = a.x;
        s_sum[4 * t + 1] = a.y;
        s_sum[4 * t + 2] = a.z;
        s_sum[4 * t + 3] = a.w;
    }
    __syncthreads();

    // phase 2: one thread per (c,b) pair
    float tot = 0.0f, den = 0.0f;
    if (t < C_ * B_) {
        const int c = t / B_;
        const float* slot = s_sum + t * 21;
        const float cnt = slot[20];
        if (s_ok[c] > 0.0f && cnt >= 2.0f) {
            float S[4][4];
            #pragma unroll
            for (int a = 0; a < 4; ++a) {
                const float zinv = 1.0f / slot[16 + a];
                #pragma unroll
                for (int g = 0; g < 4; ++g)
                    S[a][g] = slot[a * 4 + g] * zinv;
            }
            #pragma unroll
            for (int j = 0; j < 4; ++j)
                #pragma unroll
                for (int k = 0; k < 4; ++k)
                    if (k > j) {
                        const float kld = 0.5f * (S[j][j] + S[k][k] - S[j][k] - S[k][j]);
                        tot += __expf(-kld);
                    }
            den = 6.0f;   // G*(G-1)/2 pairs
        }
    }

    if (t < 128) { s_tot[t] = tot; s_den[t] = den; }
    __syncthreads();
    #pragma unroll
    for (int s = 64; s >= 1; s >>= 1) {
        if (t < s) { s_tot[t] += s_tot[t + s]; s_den[t] += s_den[t + s]; }
        __syncthreads();
    }
    if (t == 0)
        out[0] = (s_den[0] > 0.0f) ? (s_tot[0] / s_den[0]) : 0.0f;
}

extern "C" void kernel_launch(void* const* d_in, const int* in_sizes, int n_in,
                              void* d_out, int out_size, void* d_ws, size_t ws_size,
                              hipStream_t stream) {
    const float* act    = (const float*)d_in[0];  // [P,B,N,G] fp32
    const int*   labels = (const int*)d_in[1];    // [B,H,W] int32
    const float* proto  = (const float*)d_in[2];  // [120, C] fp32
    const float* gci    = (const float*)d_in[3];  // [P*G, C] fp32
    float* out = (float*)d_out;
    float* ws  = (float*)d_ws;   // 516 KiB used; every element written by stage1

    kld_stage1<<<NBLK, 256, 0, stream>>>(act, labels, gci, ws);
    kld_finalize<<<1, 1024, 0, stream>>>(ws, proto, out);
}